// Round 5
// baseline (174.139 us; speedup 1.0000x reference)
//
#include <hip/hip_runtime.h>
#include <hip/hip_bf16.h>
#include <math.h>

// BilinearGate. B=8, Cin=256, HW=9216, R=32, TRI=528, Cout=256.
// v6: SPLIT kernels, all-proven mappings (v5's operand-swapped reduce MFMA
// failed correctness; reverted to the v0-proven orientation).
// - reduce_kernel: GEMM1 streaming, A=w B=x (proven), out[b][r][px] f32 --
//   store/read pair index-isomorphic to v0's proven outS pair.
// - gemm2_kernel: v4's fused kernel minus phase-1; o[r] from 32 coalesced
//   dword loads; UPROW=300 (0 bank conflicts); depth-2 w16 pipeline + SGB;
//   3 barriers.
// - Fallback: v4 fused kernel if ws_size can't hold out[] (9.75 MB).
#define HW     9216
#define CIN    256
#define RCH    32
#define NTRI   528
#define COUT   256
#define NB     8
#define WFROWS 272   // 8 wv * 2 mi * 17 c fragment-rows of 512 halfs
#define UPROW  300   // halfs per upS row (288 data + 12 pad) = 600 B

typedef _Float16 f16x8 __attribute__((ext_vector_type(8)));
typedef _Float16 f16x4 __attribute__((ext_vector_type(4)));
typedef float    f32x4 __attribute__((ext_vector_type(4)));

struct TriTab { unsigned char i[544]; unsigned char j[544]; };
constexpr TriTab make_tri() {
  TriTab t{};
  int ii = 0, jj = 0;
  for (int k = 0; k < 544; ++k) {
    if (k < NTRI) {
      t.i[k] = (unsigned char)ii; t.j[k] = (unsigned char)jj;
      if (++jj == 32) { ++ii; jj = ii; }
    } else { t.i[k] = 0; t.j[k] = 0; }
  }
  return t;
}
constexpr TriTab TRI = make_tri();

// Wave TQ (0..7) builds its share of up[p][t] for one half.
// HALF 0: t in [TQ*36, TQ*36+36). HALF 1: t in [288+TQ*32, 288+TQ*32+32).
template<int TQ, int HALF>
__device__ __forceinline__ void build_up(const float (&o)[RCH], _Float16* rowp) {
  constexpr int NG  = HALF ? 8 : 9;
  constexpr int TLB = TQ * (HALF ? 32 : 36);
  constexpr int TB  = HALF ? 288 : 0;
#pragma unroll
  for (int g = 0; g < NG; ++g) {
    f16x4 v;
#pragma unroll
    for (int s = 0; s < 4; ++s) {
      const int tl = TLB + g * 4 + s;
      const int t  = TB + tl;
      float f = (t < NTRI) ? o[TRI.i[t]] * o[TRI.j[t]] : 0.0f;
      v[s] = (_Float16)f;
    }
    *(f16x4*)&rowp[TLB + g * 4] = v;
  }
}

template<int HALF>
__device__ __forceinline__ void build_dispatch(int wv, const float (&o)[RCH],
                                               _Float16* rowp) {
  switch (wv) {
    case 0: build_up<0, HALF>(o, rowp); break;
    case 1: build_up<1, HALF>(o, rowp); break;
    case 2: build_up<2, HALF>(o, rowp); break;
    case 3: build_up<3, HALF>(o, rowp); break;
    case 4: build_up<4, HALF>(o, rowp); break;
    case 5: build_up<5, HALF>(o, rowp); break;
    case 6: build_up<6, HALF>(o, rowp); break;
    default: build_up<7, HALF>(o, rowp); break;
  }
}

// w16 fragment layout: element (((wv*2+mi)*17 + c)*64 + lane)*8 + s holds
// w_recover[o][t] with o = wv*32+mi*16+(lane&15), t = c*32+(lane>>4)*8+s.
__global__ __launch_bounds__(256) void convert_kernel(
    const float* __restrict__ w_reduce, const float* __restrict__ w_recover,
    _Float16* __restrict__ w16, _Float16* __restrict__ wr16h,
    _Float16* __restrict__ wr16l) {
  const int bx = blockIdx.x;
  const int tid = threadIdx.x;
  if (bx < WFROWS) {
    const int wv  = bx / 34;
    const int rem = bx - wv * 34;
    const int mi  = rem / 17;
    const int c   = rem - mi * 17;
    const int lane = tid >> 2;           // 0..63
    const int s0   = (tid & 3) * 2;      // 0,2,4,6
    const int o = wv * 32 + mi * 16 + (lane & 15);
    const int t = c * 32 + (lane >> 4) * 8 + s0;
    float f0 = (t     < NTRI) ? w_recover[(size_t)o * NTRI + t]     : 0.0f;
    float f1 = (t + 1 < NTRI) ? w_recover[(size_t)o * NTRI + t + 1] : 0.0f;
    _Float16* p = &w16[((size_t)bx * 64 + lane) * 8 + s0];
    p[0] = (_Float16)f0;
    p[1] = (_Float16)f1;
  } else {
    int e = (bx - WFROWS) * 512 + tid;
#pragma unroll
    for (int k = 0; k < 2; ++k, e += 256) {
      float f = w_reduce[e];
      _Float16 h = (_Float16)f;
      wr16h[e] = h;
      wr16l[e] = (_Float16)(f - (float)h);
    }
  }
}

// ---------------- GEMM1 streaming kernel: out[b][r][px] ---------------------
// 256 thr / 4 waves; wave wv owns px subtile [p0+wv*16, +16), all 32 r.
// PROVEN v0 orientation: A = w fragment (M=r), B = x (N=px).
// D[row=q*4+reg][col=ml]: r = mt*16+q*4+reg, px = p0+wv*16+ml.
__global__ __launch_bounds__(256) void reduce_kernel(
    const float* __restrict__ x, const _Float16* __restrict__ wr16h,
    const _Float16* __restrict__ wr16l, float* __restrict__ out) {
  const int tid  = threadIdx.x;
  const int bx   = blockIdx.x;          // 1152 = 8 b * 144 px-tiles
  const int b    = bx / 144;
  const int p0   = (bx - b * 144) * 64;
  const int wv   = tid >> 6;
  const int lane = tid & 63;
  const int ml   = lane & 15;
  const int q    = lane >> 4;

  f32x4 acc[2];
#pragma unroll
  for (int mt = 0; mt < 2; ++mt)
#pragma unroll
    for (int r2 = 0; r2 < 4; ++r2) acc[mt][r2] = 0.0f;

  const float* xb = x + (size_t)b * CIN * HW + p0 + wv * 16 + ml;

  // depth-1 double buffer on the strided x loads
  float xv[2][8];
#pragma unroll
  for (int s = 0; s < 8; ++s)
    xv[0][s] = xb[(size_t)(q * 8 + s) * HW];

#pragma unroll
  for (int ch = 0; ch < 8; ++ch) {
    const int cur = ch & 1, nxt = cur ^ 1;
    if (ch < 7) {
#pragma unroll
      for (int s = 0; s < 8; ++s)
        xv[nxt][s] = xb[(size_t)((ch + 1) * 32 + q * 8 + s) * HW];
    }
    f16x8 xh, xl;
#pragma unroll
    for (int s = 0; s < 8; ++s) {
      float f = xv[cur][s];
      _Float16 h = (_Float16)f;
      xh[s] = h;
      xl[s] = (_Float16)(f - (float)h);
    }
#pragma unroll
    for (int mt = 0; mt < 2; ++mt) {
      const int off = (mt * 16 + ml) * CIN + ch * 32 + q * 8;
      f16x8 wh = *(const f16x8*)&wr16h[off];
      f16x8 wl = *(const f16x8*)&wr16l[off];
      acc[mt] = __builtin_amdgcn_mfma_f32_16x16x32_f16(wh, xh, acc[mt], 0, 0, 0);
      acc[mt] = __builtin_amdgcn_mfma_f32_16x16x32_f16(wl, xh, acc[mt], 0, 0, 0);
      acc[mt] = __builtin_amdgcn_mfma_f32_16x16x32_f16(wh, xl, acc[mt], 0, 0, 0);
    }
  }

  // out[(b*32 + r)*HW + px]: r = mt*16+q*4+reg, px = p0+wv*16+ml (coalesced)
#pragma unroll
  for (int mt = 0; mt < 2; ++mt)
#pragma unroll
    for (int reg = 0; reg < 4; ++reg)
      out[((size_t)(b * RCH + mt * 16 + q * 4 + reg)) * HW + p0 + wv * 16 + ml] =
          acc[mt][reg];
}

// ---------------- GEMM2 kernel: up-build + 17 chunks ------------------------
__global__ __launch_bounds__(512, 4) void gemm2_kernel(
    const float* __restrict__ outp, const _Float16* __restrict__ w16,
    float* __restrict__ y) {
  __shared__ __align__(16) _Float16 upS[64 * UPROW];   // 38.4 KB (only LDS)

  const int tid  = threadIdx.x;
  const int bx   = blockIdx.x;          // 1152 = 8 b * 144 px-tiles
  const int b    = bx / 144;
  const int p0   = (bx - b * 144) * 64;
  const int wv   = tid >> 6;
  const int lane = tid & 63;
  const int ml   = lane & 15;
  const int q    = lane >> 4;

  // o-vector: lane owns px = p0+lane; 32 coalesced dword loads (L2/L3-hot).
  const float* ob = outp + (size_t)b * RCH * HW + p0 + lane;
  float o0[RCH];
#pragma unroll
  for (int r = 0; r < RCH; ++r) o0[r] = ob[(size_t)r * HW];

  // Fragment bases into pre-swizzled w16 (chunk c at +c*512 halfs).
  const _Float16* wf0 = w16 + ((size_t)(wv * 2 + 0) * 17 * 64 + lane) * 8;
  const _Float16* wf1 = w16 + ((size_t)(wv * 2 + 1) * 17 * 64 + lane) * 8;

  // A-stream depth-2 prologue: chunks 0,1 in flight during build0.
  f16x8 abuf[3][2];
  abuf[0][0] = *(const f16x8*)&wf0[0];
  abuf[0][1] = *(const f16x8*)&wf1[0];
  abuf[1][0] = *(const f16x8*)&wf0[512];
  abuf[1][1] = *(const f16x8*)&wf1[512];

  f32x4 acc[2][4];
#pragma unroll
  for (int mi = 0; mi < 2; ++mi)
#pragma unroll
    for (int ni = 0; ni < 4; ++ni)
#pragma unroll
      for (int r2 = 0; r2 < 4; ++r2) acc[mi][ni][r2] = 0.0f;

  _Float16* rowp = &upS[lane * UPROW];

  // ---------------- HALF 0: build t[0,288) then chunks c=0..8 -------------
  build_dispatch<0>(wv, o0, rowp);
  __syncthreads();   // barrier 1: upS half0 ready

  f16x8 bbuf[2][4];
#pragma unroll
  for (int ni = 0; ni < 4; ++ni)
    bbuf[0][ni] = *(const f16x8*)&upS[(ni * 16 + ml) * UPROW + q * 8];

#pragma unroll
  for (int c = 0; c < 9; ++c) {
    const int cur = c % 3;
    const int pf  = (c + 2) % 3;     // chunks c+2 <= 10 < 17: always valid
    abuf[pf][0] = *(const f16x8*)&wf0[(size_t)(c + 2) * 512];
    abuf[pf][1] = *(const f16x8*)&wf1[(size_t)(c + 2) * 512];
    const int cb = c & 1, nb = cb ^ 1;
    if (c < 8) {
      const int t0n = (c + 1) * 32;
#pragma unroll
      for (int ni = 0; ni < 4; ++ni)
        bbuf[nb][ni] = *(const f16x8*)&upS[(ni * 16 + ml) * UPROW + t0n + q * 8];
    }
#pragma unroll
    for (int ni = 0; ni < 4; ++ni) {
      acc[0][ni] = __builtin_amdgcn_mfma_f32_16x16x32_f16(abuf[cur][0], bbuf[cb][ni], acc[0][ni], 0, 0, 0);
      acc[1][ni] = __builtin_amdgcn_mfma_f32_16x16x32_f16(abuf[cur][1], bbuf[cb][ni], acc[1][ni], 0, 0, 0);
    }
    __builtin_amdgcn_sched_group_barrier(0x020, 2, 0);     // A prefetch
    if (c < 8)
      __builtin_amdgcn_sched_group_barrier(0x100, 4, 0);   // B ds_reads
    __builtin_amdgcn_sched_group_barrier(0x008, 8, 0);     // MFMAs
  }

  // Reload o (L2-hot, coalesced); in flight across the barrier.
  float o1[RCH];
#pragma unroll
  for (int r = 0; r < RCH; ++r) o1[r] = ob[(size_t)r * HW];

  __syncthreads();   // barrier 2: half0 reads done (WAR before overwrite)

  // ---------------- HALF 1: build t[288,544) then chunks g=9..16 ----------
  build_dispatch<1>(wv, o1, rowp);
  __syncthreads();   // barrier 3: upS half1 ready
  // abuf slots hold chunk 9 (slot 0) and 10 (slot 1).

#pragma unroll
  for (int ni = 0; ni < 4; ++ni)
    bbuf[0][ni] = *(const f16x8*)&upS[(ni * 16 + ml) * UPROW + q * 8];

#pragma unroll
  for (int cc = 0; cc < 8; ++cc) {
    const int cur = cc % 3;          // global chunk g=9+cc, (9+cc)%3 == cc%3
    if (cc < 6) {
      const int pf = (2 + cc) % 3;   // chunk 11+cc, valid while 11+cc <= 16
      abuf[pf][0] = *(const f16x8*)&wf0[(size_t)(11 + cc) * 512];
      abuf[pf][1] = *(const f16x8*)&wf1[(size_t)(11 + cc) * 512];
    }
    const int cb = cc & 1, nb = cb ^ 1;
    if (cc < 7) {
      const int t0n = (cc + 1) * 32;
#pragma unroll
      for (int ni = 0; ni < 4; ++ni)
        bbuf[nb][ni] = *(const f16x8*)&upS[(ni * 16 + ml) * UPROW + t0n + q * 8];
    }
#pragma unroll
    for (int ni = 0; ni < 4; ++ni) {
      acc[0][ni] = __builtin_amdgcn_mfma_f32_16x16x32_f16(abuf[cur][0], bbuf[cb][ni], acc[0][ni], 0, 0, 0);
      acc[1][ni] = __builtin_amdgcn_mfma_f32_16x16x32_f16(abuf[cur][1], bbuf[cb][ni], acc[1][ni], 0, 0, 0);
    }
    if (cc < 6)
      __builtin_amdgcn_sched_group_barrier(0x020, 2, 0);   // A prefetch
    if (cc < 7)
      __builtin_amdgcn_sched_group_barrier(0x100, 4, 0);   // B ds_reads
    __builtin_amdgcn_sched_group_barrier(0x008, 8, 0);     // MFMAs
  }

  // ---------------- Epilogue: signed sqrt, dword stores -------------------
#pragma unroll
  for (int mi = 0; mi < 2; ++mi) {
#pragma unroll
    for (int reg = 0; reg < 4; ++reg) {
      const int o = wv * 32 + mi * 16 + q * 4 + reg;
      float* yrow = y + ((size_t)(b * COUT + o)) * HW + p0 + ml;
#pragma unroll
      for (int ni = 0; ni < 4; ++ni) {
        float v = acc[mi][ni][reg];
        float s = sqrtf(fabsf(v) + 1e-6f);
        yrow[ni * 16] = v > 0.0f ? s : (v < 0.0f ? -s : 0.0f);
      }
    }
  }
}

// ---------------- Fallback fused kernel (v4, proven) if ws too small -------
__global__ __launch_bounds__(512, 4) void fused_kernel(
    const float* __restrict__ x, const _Float16* __restrict__ w16,
    const _Float16* __restrict__ wr16h, const _Float16* __restrict__ wr16l,
    float* __restrict__ y) {
  __shared__ float outS[RCH * 68];
  __shared__ __align__(16) _Float16 upS[64 * UPROW];

  const int tid  = threadIdx.x;
  const int bx   = blockIdx.x;
  const int b    = bx / 144;
  const int p0   = (bx - b * 144) * 64;
  const int wv   = tid >> 6;
  const int lane = tid & 63;
  const int ml   = lane & 15;
  const int q    = lane >> 4;
  const int mt   = wv >> 2;
  const int nt   = wv & 3;

  {
    f32x4 g1acc;
#pragma unroll
    for (int r2 = 0; r2 < 4; ++r2) g1acc[r2] = 0.0f;

    const int abase = (mt * 16 + ml) * CIN + q * 8;
    f16x8 pa[3][2];
    pa[0][0] = *(const f16x8*)&wr16h[abase + 0 * 32];
    pa[0][1] = *(const f16x8*)&wr16l[abase + 0 * 32];
    pa[1][0] = *(const f16x8*)&wr16h[abase + 1 * 32];
    pa[1][1] = *(const f16x8*)&wr16l[abase + 1 * 32];

    const float* xb = x + (size_t)b * CIN * HW + p0 + nt * 16 + ml;
    float xv[64];
#pragma unroll
    for (int ch = 0; ch < 8; ++ch)
#pragma unroll
      for (int s = 0; s < 8; ++s)
        xv[ch * 8 + s] = xb[(size_t)(ch * 32 + q * 8 + s) * HW];
    __builtin_amdgcn_sched_barrier(0);

#pragma unroll
    for (int ch = 0; ch < 8; ++ch) {
      const int cur = ch % 3;
      if (ch + 2 < 8) {
        const int pf = (ch + 2) % 3;
        pa[pf][0] = *(const f16x8*)&wr16h[abase + (ch + 2) * 32];
        pa[pf][1] = *(const f16x8*)&wr16l[abase + (ch + 2) * 32];
      }
      f16x8 bh, bl;
#pragma unroll
      for (int s = 0; s < 8; ++s) {
        float f = xv[ch * 8 + s];
        _Float16 h = (_Float16)f;
        bh[s] = h;
        bl[s] = (_Float16)(f - (float)h);
      }
      g1acc = __builtin_amdgcn_mfma_f32_16x16x32_f16(pa[cur][0], bh, g1acc, 0, 0, 0);
      g1acc = __builtin_amdgcn_mfma_f32_16x16x32_f16(pa[cur][1], bh, g1acc, 0, 0, 0);
      g1acc = __builtin_amdgcn_mfma_f32_16x16x32_f16(pa[cur][0], bl, g1acc, 0, 0, 0);
    }
#pragma unroll
    for (int reg = 0; reg < 4; ++reg)
      outS[(mt * 16 + q * 4 + reg) * 68 + nt * 16 + ml] = g1acc[reg];
  }

  const _Float16* wf0 = w16 + ((size_t)(wv * 2 + 0) * 17 * 64 + lane) * 8;
  const _Float16* wf1 = w16 + ((size_t)(wv * 2 + 1) * 17 * 64 + lane) * 8;

  f16x8 abuf[3][2];
  abuf[0][0] = *(const f16x8*)&wf0[0];
  abuf[0][1] = *(const f16x8*)&wf1[0];
  abuf[1][0] = *(const f16x8*)&wf0[512];
  abuf[1][1] = *(const f16x8*)&wf1[512];

  __syncthreads();

  f32x4 acc[2][4];
#pragma unroll
  for (int mi = 0; mi < 2; ++mi)
#pragma unroll
    for (int ni = 0; ni < 4; ++ni)
#pragma unroll
      for (int r2 = 0; r2 < 4; ++r2) acc[mi][ni][r2] = 0.0f;

  _Float16* rowp = &upS[lane * UPROW];

  {
    float o[RCH];
#pragma unroll
    for (int r = 0; r < RCH; ++r) o[r] = outS[r * 68 + lane];
    build_dispatch<0>(wv, o, rowp);
  }
  __syncthreads();

  f16x8 bbuf[2][4];
#pragma unroll
  for (int ni = 0; ni < 4; ++ni)
    bbuf[0][ni] = *(const f16x8*)&upS[(ni * 16 + ml) * UPROW + q * 8];

#pragma unroll
  for (int c = 0; c < 9; ++c) {
    const int cur = c % 3;
    const int pf  = (c + 2) % 3;
    abuf[pf][0] = *(const f16x8*)&wf0[(size_t)(c + 2) * 512];
    abuf[pf][1] = *(const f16x8*)&wf1[(size_t)(c + 2) * 512];
    const int cb = c & 1, nb = cb ^ 1;
    if (c < 8) {
      const int t0n = (c + 1) * 32;
#pragma unroll
      for (int ni = 0; ni < 4; ++ni)
        bbuf[nb][ni] = *(const f16x8*)&upS[(ni * 16 + ml) * UPROW + t0n + q * 8];
    }
#pragma unroll
    for (int ni = 0; ni < 4; ++ni) {
      acc[0][ni] = __builtin_amdgcn_mfma_f32_16x16x32_f16(abuf[cur][0], bbuf[cb][ni], acc[0][ni], 0, 0, 0);
      acc[1][ni] = __builtin_amdgcn_mfma_f32_16x16x32_f16(abuf[cur][1], bbuf[cb][ni], acc[1][ni], 0, 0, 0);
    }
  }
  __syncthreads();

  {
    float o[RCH];
#pragma unroll
    for (int r = 0; r < RCH; ++r) o[r] = outS[r * 68 + lane];
    build_dispatch<1>(wv, o, rowp);
  }
  __syncthreads();

#pragma unroll
  for (int ni = 0; ni < 4; ++ni)
    bbuf[0][ni] = *(const f16x8*)&upS[(ni * 16 + ml) * UPROW + q * 8];

#pragma unroll
  for (int cc = 0; cc < 8; ++cc) {
    const int cur = cc % 3;
    if (cc < 6) {
      const int pf = (2 + cc) % 3;
      abuf[pf][0] = *(const f16x8*)&wf0[(size_t)(11 + cc) * 512];
      abuf[pf][1] = *(const f16x8*)&wf1[(size_t)(11 + cc) * 512];
    }
    const int cb = cc & 1, nb = cb ^ 1;
    if (cc < 7) {
      const int t0n = (cc + 1) * 32;
#pragma unroll
      for (int ni = 0; ni < 4; ++ni)
        bbuf[nb][ni] = *(const f16x8*)&upS[(ni * 16 + ml) * UPROW + t0n + q * 8];
    }
#pragma unroll
    for (int ni = 0; ni < 4; ++ni) {
      acc[0][ni] = __builtin_amdgcn_mfma_f32_16x16x32_f16(abuf[cur][0], bbuf[cb][ni], acc[0][ni], 0, 0, 0);
      acc[1][ni] = __builtin_amdgcn_mfma_f32_16x16x32_f16(abuf[cur][1], bbuf[cb][ni], acc[1][ni], 0, 0, 0);
    }
  }

#pragma unroll
  for (int mi = 0; mi < 2; ++mi) {
#pragma unroll
    for (int reg = 0; reg < 4; ++reg) {
      const int o = wv * 32 + mi * 16 + q * 4 + reg;
      float* yrow = y + ((size_t)(b * COUT + o)) * HW + p0 + ml;
#pragma unroll
      for (int ni = 0; ni < 4; ++ni) {
        float v = acc[mi][ni][reg];
        float s = sqrtf(fabsf(v) + 1e-6f);
        yrow[ni * 16] = v > 0.0f ? s : (v < 0.0f ? -s : 0.0f);
      }
    }
  }
}

extern "C" void kernel_launch(void* const* d_in, const int* in_sizes, int n_in,
                              void* d_out, int out_size, void* d_ws, size_t ws_size,
                              hipStream_t stream) {
  const float* x         = (const float*)d_in[0];
  const float* w_reduce  = (const float*)d_in[1];
  const float* w_recover = (const float*)d_in[2];
  float* y = (float*)d_out;

  _Float16* w16   = (_Float16*)d_ws;                            // 278528 B
  _Float16* wr16h = (_Float16*)((char*)d_ws + 278528);          // 16384 B
  _Float16* wr16l = (_Float16*)((char*)d_ws + 278528 + 16384);  // 16384 B
  float*    outp  = (float*)((char*)d_ws + 311296);             // 9437184 B
  const size_t NEED = 311296 + (size_t)NB * RCH * HW * 4;

  convert_kernel<<<WFROWS + 16, 256, 0, stream>>>(w_reduce, w_recover, w16, wr16h, wr16l);
  if (ws_size >= NEED) {
    reduce_kernel<<<NB * (HW / 64), 256, 0, stream>>>(x, wr16h, wr16l, outp);
    gemm2_kernel<<<NB * (HW / 64), 512, 0, stream>>>(outp, w16, y);
  } else {
    fused_kernel<<<NB * (HW / 64), 512, 0, stream>>>(x, w16, wr16h, wr16l, y);
  }
}